// Round 6
// baseline (251.370 us; speedup 1.0000x reference)
//
#include <hip/hip_runtime.h>

// pyGAMNet round 5 kernel (re-submit; R5 bench was a broker timeout).
// Weights staged in LDS (wave-uniform broadcast reads), 1 feature/wave,
// launch_bounds(256,8) to cap VGPR<=64.
// Theory: R4 was scalar-cache-thrash latency-bound (real VALU busy ~46%).

constexpr int NCOLS = 64;
constexpr int NNUM  = 48;
constexpr int NCAT  = 16;
constexpr int NCLS  = 32;
constexpr int H0N   = 40;
constexpr int H1N   = 20;

#define BLOCK 256
#define RG    64     // rows per block (lane = row)
#define FPB   4      // numeric features per block (one per wave)
#define TP    5      // numeric out-tile pad stride (4 used)
#define TP16  20     // cat out-tile pad stride (16 used, 16B-aligned rows)

// one shared pool, carved per branch (numeric needs ~16KB; cat ~6KB)
#define SM_FLOATS 4008

__global__ __launch_bounds__(BLOCK, 8)
void gam_kernel(const float* __restrict__ inp,
                const float* __restrict__ W0, const float* __restrict__ b0,
                const float* __restrict__ W1, const float* __restrict__ b1,
                const float* __restrict__ W2, const float* __restrict__ b2,
                const float* __restrict__ cbias,
                float* __restrict__ out)
{
    __shared__ float smem[SM_FLOATS];

    const int t    = threadIdx.x;
    const int lane = t & 63;
    const int wv   = __builtin_amdgcn_readfirstlane(t >> 6);
    const int yg   = blockIdx.y;                 // 0..11 numeric, 12 cat
    const long long row0 = (long long)blockIdx.x * RG;
    const float* __restrict__ rowp = inp + (row0 + lane) * NCOLS;

    if (yg < 12) {
        // ---- LDS carve (floats): w1s[3200] w0s[160] b0s[160] b1s[80] w2s[80] b2s[4] tile[320]
        float* w1s  = smem;            // [f][k][o]
        float* w0s  = smem + 3200;
        float* b0s  = smem + 3360;
        float* b1s  = smem + 3520;
        float* w2s  = smem + 3600;
        float* b2s  = smem + 3680;
        float* tile = smem + 3684;     // 3684*4 B is 16B-aligned

        const int fbase = yg * FPB;

        // stage weights: contiguous float4 global->LDS copies
        {
            const float4* s = reinterpret_cast<const float4*>(W1 + fbase * H0N * H1N);
            float4* d = reinterpret_cast<float4*>(w1s);
            #pragma unroll
            for (int j = 0; j < (FPB * H0N * H1N / 4) / BLOCK + 1; ++j) {
                int i = j * BLOCK + t;
                if (i < FPB * H0N * H1N / 4) d[i] = s[i];
            }
        }
        if (t < FPB * H0N / 4) {       // 40 threads
            reinterpret_cast<float4*>(w0s)[t] = reinterpret_cast<const float4*>(W0 + fbase * H0N)[t];
            reinterpret_cast<float4*>(b0s)[t] = reinterpret_cast<const float4*>(b0 + fbase * H0N)[t];
        }
        if (t < FPB * H1N / 4) {       // 20 threads
            reinterpret_cast<float4*>(b1s)[t] = reinterpret_cast<const float4*>(b1 + fbase * H1N)[t];
            reinterpret_cast<float4*>(w2s)[t] = reinterpret_cast<const float4*>(W2 + fbase * H1N)[t];
        }
        if (t < FPB) b2s[t] = b2[fbase + t];
        __syncthreads();

        // ---- compute: wave wv owns feature fbase+wv for 64 rows (lane = row)
        const int f = fbase + wv;
        const float x = rowp[f];
        const float* __restrict__ wf1 = w1s + wv * H0N * H1N;
        const float* __restrict__ wf0 = w0s + wv * H0N;
        const float* __restrict__ bf0 = b0s + wv * H0N;

        float h1[H1N];
        #pragma unroll
        for (int o = 0; o < H1N; ++o) h1[o] = b1s[wv * H1N + o];

        #pragma unroll
        for (int k = 0; k < H0N; ++k) {
            const float h0k = fmaxf(fmaf(x, wf0[k], bf0[k]), 0.0f);
            #pragma unroll
            for (int o = 0; o < H1N; ++o)
                h1[o] = fmaf(h0k, wf1[k * H1N + o], h1[o]);   // ds broadcast weight
        }

        float acc = b2s[wv];
        #pragma unroll
        for (int o = 0; o < H1N; ++o)
            acc = fmaf(fmaxf(h1[o], 0.0f), w2s[wv * H1N + o], acc);

        tile[lane * TP + wv] = acc;
        __syncthreads();

        // store 64 rows x 4 cols, one dword/thread (16B segments per row)
        const int r = t >> 2, c = t & 3;
        out[(row0 + r) * NCOLS + fbase + c] = tile[r * TP + c];
    } else {
        // ---- categorical: features 48..63, 4 per wave
        float* cb     = smem;               // 512 floats
        float* tile16 = smem + 512;         // [64][TP16]

        for (int i = t; i < NCAT * NCLS; i += BLOCK) cb[i] = cbias[i];
        __syncthreads();

        const int jbase = wv * 4;
        #pragma unroll
        for (int ff = 0; ff < 4; ++ff) {
            const int j = jbase + ff;
            const int idx = (int)rowp[NNUM + j];
            tile16[lane * TP16 + j] = cb[j * NCLS + idx];
        }
        __syncthreads();

        // store 64 rows x 16 cols, one float4/thread
        const int r = t >> 2, c4 = t & 3;
        const float* src = &tile16[r * TP16 + c4 * 4];
        float4 v = make_float4(src[0], src[1], src[2], src[3]);
        *reinterpret_cast<float4*>(out + (row0 + r) * NCOLS + NNUM + c4 * 4) = v;
    }
}

extern "C" void kernel_launch(void* const* d_in, const int* in_sizes, int n_in,
                              void* d_out, int out_size, void* d_ws, size_t ws_size,
                              hipStream_t stream) {
    const float* inp   = (const float*)d_in[0];
    const float* W0    = (const float*)d_in[1];
    const float* b0    = (const float*)d_in[2];
    const float* W1    = (const float*)d_in[3];
    const float* b1    = (const float*)d_in[4];
    const float* W2    = (const float*)d_in[5];
    const float* b2    = (const float*)d_in[6];
    const float* cbias = (const float*)d_in[7];
    float* out = (float*)d_out;

    const int nrows = 131072;
    dim3 grid(nrows / RG, 13);   // 2048 x (12 numeric + 1 cat)
    dim3 block(BLOCK);
    gam_kernel<<<grid, block, 0, stream>>>(inp, W0, b0, W1, b1, W2, b2, cbias, out);
}